// Round 2
// baseline (527.417 us; speedup 1.0000x reference)
//
#include <hip/hip_runtime.h>
#include <hip/hip_bf16.h>
#include <math.h>

#define MDIM  128
#define FEAT  8256      // 128*129/2 (elements == bytes in fp8)
#define HID   1651
#define HIDP  1664      // 13*128, zero-padded
#define BATCH 4096
#define BK    64
#define KT_TOTAL 129    // FEAT / BK
#define NZ    2
#define KT_PER 64       // z=0: 64 iters, z=1: 65 iters
#define W1SCALE 8192.0f
#define W1INV   (1.0f / 8192.0f)
#define DEPTH 3         // LDS ring buffers (2-iteration prefetch lead)

using f32x4  = __attribute__((ext_vector_type(4))) float;
using f32x16 = __attribute__((ext_vector_type(16))) float;
using i32x4  = __attribute__((ext_vector_type(4))) int;
using i32x8  = __attribute__((ext_vector_type(8))) int;
using bf16x8 = __attribute__((ext_vector_type(8))) __bf16;
typedef long long i64;

__device__ __forceinline__ void gload_lds16(const void* g, void* l) {
    __builtin_amdgcn_global_load_lds(
        (const __attribute__((address_space(1))) void*)g,
        (__attribute__((address_space(3))) void*)l,
        16, 0, 0);
}

__device__ __forceinline__ int row_off(int i) { return (i * (257 - i)) >> 1; }

// pack 8 floats -> 8 fp8 e4m3 bytes (two ints)
__device__ __forceinline__ void pack8_fp8(const float* f, int* o) {
    int lo = __builtin_amdgcn_cvt_pk_fp8_f32(f[0], f[1], 0, false);
    lo     = __builtin_amdgcn_cvt_pk_fp8_f32(f[2], f[3], lo, true);
    int hi = __builtin_amdgcn_cvt_pk_fp8_f32(f[4], f[5], 0, false);
    hi     = __builtin_amdgcn_cvt_pk_fp8_f32(f[6], f[7], hi, true);
    o[0] = lo; o[1] = hi;
}

// ---------------------------------------------------------------------------
// Kernel 1 (fused prep): blocks [0, BATCH) gather triu(sim) -> X fp8;
// blocks [BATCH, BATCH+5*HIDP) convert W1*8192 -> fp8 [HIDP, FEAT] (rows >=
// HID zeroed). Unchanged from round 1 (verified).
// ---------------------------------------------------------------------------
__global__ void __launch_bounds__(256)
prep_kernel(const float* __restrict__ sim, const float* __restrict__ W1,
            char* __restrict__ X, char* __restrict__ W1p) {
    const int t = threadIdx.x;
    if (blockIdx.x < BATCH) {
        const int b = blockIdx.x;
        const float* srow = sim + ((i64)b << 14);
        char* dst = X + (i64)b * FEAT;
#pragma unroll
        for (int it = 0; it < 5; ++it) {
            const int w = it * 256 + t;
            if (w < FEAT / 8) {
                const int f0 = w * 8;
                int i = (int)((257.0f - sqrtf(66049.0f - 8.0f * (float)f0)) * 0.5f);
                i = i < 0 ? 0 : (i > 127 ? 127 : i);
                while (i < 127 && row_off(i + 1) <= f0) ++i;
                while (i > 0 && row_off(i) > f0) --i;
                int j = i + (f0 - row_off(i));
                float v[8];
#pragma unroll
                for (int e = 0; e < 8; ++e) {
                    if (j > 127) { ++i; j = i; }
                    v[e] = srow[i * MDIM + j];
                    ++j;
                }
                int o[2];
                pack8_fp8(v, o);
                *(int2*)(dst + f0) = make_int2(o[0], o[1]);
            }
        }
    } else {
        const int c  = blockIdx.x - BATCH;   // 0 .. 5*HIDP-1
        const int wb = c % 5;
        const int n  = c / 5;
        const int w  = wb * 256 + t;
        if (w >= FEAT / 8) return;
        const int f0 = w * 8;
        int o[2];
        if (n < HID) {
            const float* src = W1 + (i64)n * FEAT + f0;
            const f32x4 a = *(const f32x4*)src;
            const f32x4 d = *(const f32x4*)(src + 4);
            float v[8];
#pragma unroll
            for (int e = 0; e < 4; ++e) {
                v[e]     = a[e] * W1SCALE;
                v[e + 4] = d[e] * W1SCALE;
            }
            pack8_fp8(v, o);
        } else {
            o[0] = 0; o[1] = 0;
        }
        *(int2*)(W1p + (i64)n * FEAT + f0) = make_int2(o[0], o[1]);
    }
}

// ---------------------------------------------------------------------------
// Kernel 2: split-K (NZ=2) MX-scaled fp8 GEMM, 128x128 tile, BK=64.
// Round-2 change: 3-deep LDS ring + RAW s_barrier + COUNTED s_waitcnt vmcnt
// (catalog T4). __syncthreads' implicit vmcnt(0) drained the prefetch every
// K-step (round-1 regression); counted waits keep 2 tiles of staging in
// flight across barriers (~2-iteration lead > L2/L3 latency).
//
// LDS layout (HW-verified round 1): phys(row,chunk)=chunk*2048+row*16 per
// buffer; staging realizes it by per-lane global source swizzle; reads are
// two conflict-free ds_read_b128 per 32B fragment.
// ---------------------------------------------------------------------------
__global__ void __launch_bounds__(256, 3)
gemm_split_kernel(const char* __restrict__ X,
                  const char* __restrict__ W1p,
                  __hip_bfloat16* __restrict__ Cz) {
    __shared__ __align__(16) char lds_a[DEPTH * 8192];   // 24 KB
    __shared__ __align__(16) char lds_b[DEPTH * 8192];   // 24 KB

    const int t    = threadIdx.x;
    const int w    = t >> 6;
    const int l    = t & 63;
    const int bm   = blockIdx.x;
    const int bn   = blockIdx.y;
    const int z    = blockIdx.z;
    const int wm   = w >> 1;          // wave row (0..1) -> 64 output rows
    const int wn   = w & 1;           // wave col (0..1) -> 64 output cols
    const int lm   = l & 31;
    const int c0   = (l >> 5) << 1;   // chunk base for this lane's K-half

    f32x16 acc[2][2];
#pragma unroll
    for (int r = 0; r < 16; ++r) {
        acc[0][0][r] = 0.f; acc[0][1][r] = 0.f;
        acc[1][0][r] = 0.f; acc[1][1][r] = 0.f;
    }

    const int kt0 = z * KT_PER;
    const int nkt = (z == NZ - 1) ? (KT_TOTAL - KT_PER * (NZ - 1)) : KT_PER;

    // staging roles: thread t covers row (w&1)*64+l, chunks {(w>>1), (w>>1)+2}
    const int stR = ((w & 1) << 6) + l;
    const char* gA0 = X + (i64)(bm * 128 + stR) * FEAT + kt0 * BK + (w >> 1) * 16;
    const char* gB0 = W1p + (i64)(bn * 128 + stR) * FEAT + kt0 * BK + (w >> 1) * 16;
    char* lA = lds_a + w * 1024;      // wave-uniform LDS dest base
    char* lB = lds_b + w * 1024;

    // 4 vmcnt events (global_load_lds) per STAGE per thread
#define STAGE(buf, kidx) do {                                      \
        const char* _ga = gA0 + (i64)(kidx) * BK;                  \
        const char* _gb = gB0 + (i64)(kidx) * BK;                  \
        char* _la = lA + (buf) * 8192;                             \
        char* _lb = lB + (buf) * 8192;                             \
        gload_lds16(_ga,      _la);                                \
        gload_lds16(_ga + 32, _la + 4096);                         \
        gload_lds16(_gb,      _lb);                                \
        gload_lds16(_gb + 32, _lb + 4096);                         \
    } while (0)

    // prologue: fill the ring (nkt >= 64 > DEPTH always)
    STAGE(0, 0);
    STAGE(1, 1);
    STAGE(2, 2);

    int cur = 0;
    for (int kt = 0; kt < nkt; ++kt) {
        // ready-wait for buf[cur]: drain my oldest stage, keep the rest flying
        if (kt + 3 <= nkt)      asm volatile("s_waitcnt vmcnt(8)" ::: "memory");
        else if (kt + 2 == nkt) asm volatile("s_waitcnt vmcnt(4)" ::: "memory");
        else                    asm volatile("s_waitcnt vmcnt(0)" ::: "memory");
        __builtin_amdgcn_s_barrier();          // all waves' quarters landed
        __builtin_amdgcn_sched_barrier(0);

        const char* pa = lds_a + cur * 8192 + c0 * 2048 + (wm * 64 + lm) * 16;
        const char* pb = lds_b + cur * 8192 + c0 * 2048 + (wn * 64 + lm) * 16;
        i32x8 A0, A1, B0, B1;
        *((i32x4*)&A0)     = *(const i32x4*)(pa);
        *((i32x4*)&A0 + 1) = *(const i32x4*)(pa + 2048);
        *((i32x4*)&A1)     = *(const i32x4*)(pa + 512);
        *((i32x4*)&A1 + 1) = *(const i32x4*)(pa + 512 + 2048);
        *((i32x4*)&B0)     = *(const i32x4*)(pb);
        *((i32x4*)&B0 + 1) = *(const i32x4*)(pb + 2048);
        *((i32x4*)&B1)     = *(const i32x4*)(pb + 512);
        *((i32x4*)&B1 + 1) = *(const i32x4*)(pb + 512 + 2048);

        __builtin_amdgcn_s_setprio(1);
        // fmt 0 = OCP fp8 e4m3; unit scales (0x7F = 2^0) in every byte
        acc[0][0] = __builtin_amdgcn_mfma_scale_f32_32x32x64_f8f6f4(
            A0, B0, acc[0][0], 0, 0, 0, 0x7F7F7F7F, 0, 0x7F7F7F7F);
        acc[0][1] = __builtin_amdgcn_mfma_scale_f32_32x32x64_f8f6f4(
            A0, B1, acc[0][1], 0, 0, 0, 0x7F7F7F7F, 0, 0x7F7F7F7F);
        acc[1][0] = __builtin_amdgcn_mfma_scale_f32_32x32x64_f8f6f4(
            A1, B0, acc[1][0], 0, 0, 0, 0x7F7F7F7F, 0, 0x7F7F7F7F);
        acc[1][1] = __builtin_amdgcn_mfma_scale_f32_32x32x64_f8f6f4(
            A1, B1, acc[1][1], 0, 0, 0, 0x7F7F7F7F, 0, 0x7F7F7F7F);
        __builtin_amdgcn_s_setprio(0);

        // my ds_reads retired before anyone overwrites buf[cur]
        asm volatile("s_waitcnt lgkmcnt(0)" ::: "memory");
        __builtin_amdgcn_sched_barrier(0);
        __builtin_amdgcn_s_barrier();          // all waves done reading cur
        __builtin_amdgcn_sched_barrier(0);

        if (kt + 3 < nkt) STAGE(cur, kt + 3);  // refill oldest slot
        cur = (cur == DEPTH - 1) ? 0 : cur + 1;
    }
#undef STAGE

    // 32x32 C/D mapping: col = lane&31, row = (reg&3) + 8*(reg>>2) + 4*(lane>>5)
    __hip_bfloat16* cz = Cz + ((i64)z * BATCH + bm * 128) * HIDP
                            + bn * 128 + wn * 64;
#pragma unroll
    for (int rb = 0; rb < 2; ++rb)
#pragma unroll
        for (int cb = 0; cb < 2; ++cb) {
#pragma unroll
            for (int reg = 0; reg < 16; ++reg) {
                const int row = (reg & 3) + ((reg >> 2) << 3) + ((l >> 5) << 2);
                const int ml  = wm * 64 + rb * 32 + row;
                cz[(i64)ml * HIDP + cb * 32 + lm] =
                    __float2bfloat16(acc[rb][cb][reg]);
            }
        }
}

// ---------------------------------------------------------------------------
// Kernel 3: out[b] = sigmoid(b2 + sum_n relu((Cz0+Cz1)*W1INV + b1[n]) * W2[n])
// ---------------------------------------------------------------------------
__global__ void __launch_bounds__(256)
epilogue_kernel(const __hip_bfloat16* __restrict__ Cz,
                const float* __restrict__ b1,
                const float* __restrict__ W2,
                const float* __restrict__ b2,
                float* __restrict__ out) {
    const int b = blockIdx.x;
    const int t = threadIdx.x;
    float sum = 0.0f;
    const bf16x8* r0 = (const bf16x8*)(Cz + (i64)b * HIDP);
    const bf16x8* r1 = (const bf16x8*)(Cz + ((i64)BATCH + b) * HIDP);
    if (t < HIDP / 8) {   // 208 active threads, one pass
        const bf16x8 a = r0[t];
        const bf16x8 c = r1[t];
#pragma unroll
        for (int e = 0; e < 8; ++e) {
            const int n = t * 8 + e;
            if (n < HID) {
                const float v = ((float)a[e] + (float)c[e]) * W1INV + b1[n];
                sum += fmaxf(v, 0.0f) * W2[n];
            }
        }
    }
    sum += __shfl_xor(sum, 1);
    sum += __shfl_xor(sum, 2);
    sum += __shfl_xor(sum, 4);
    sum += __shfl_xor(sum, 8);
    sum += __shfl_xor(sum, 16);
    sum += __shfl_xor(sum, 32);
    __shared__ float wsum[4];
    if ((t & 63) == 0) wsum[t >> 6] = sum;
    __syncthreads();
    if (t == 0) {
        const float s = wsum[0] + wsum[1] + wsum[2] + wsum[3];
        out[b] = 1.0f / (1.0f + expf(-(s + b2[0])));
    }
}

extern "C" void kernel_launch(void* const* d_in, const int* in_sizes, int n_in,
                              void* d_out, int out_size, void* d_ws, size_t ws_size,
                              hipStream_t stream) {
    const float* sim = (const float*)d_in[0];
    const float* W1  = (const float*)d_in[1];
    const float* b1  = (const float*)d_in[2];
    const float* W2  = (const float*)d_in[3];
    const float* b2  = (const float*)d_in[4];
    float* out = (float*)d_out;

    char* ws = (char*)d_ws;
    const i64 X_OFF   = 0;                       // 33,816,576 B
    const i64 W1P_OFF = (i64)BATCH * FEAT;       // fp8: elems == bytes
    const i64 CZ_OFF  = W1P_OFF + (i64)HIDP * FEAT;  // +13,737,984
    // Cz: NZ*BATCH*HIDP*2 = 27,262,976 B; total 74,817,536 < proven ws bound
    char*           Xf8  = ws + X_OFF;
    char*           W1f8 = ws + W1P_OFF;
    __hip_bfloat16* Cz   = (__hip_bfloat16*)(ws + CZ_OFF);

    prep_kernel<<<BATCH + 5 * HIDP, 256, 0, stream>>>(sim, W1, Xf8, W1f8);
    {
        dim3 grid(BATCH / 128, HIDP / 128, NZ);        // (32, 13, 2)
        gemm_split_kernel<<<grid, 256, 0, stream>>>(Xf8, W1f8, Cz);
    }
    epilogue_kernel<<<BATCH, 256, 0, stream>>>(Cz, b1, W2, b2, out);
}

// Round 3
// 501.889 us; speedup vs baseline: 1.0509x; 1.0509x over previous
//
#include <hip/hip_runtime.h>
#include <hip/hip_bf16.h>
#include <math.h>

#define MDIM  128
#define FEAT  8256      // 128*129/2 (elements == bytes in fp8)
#define HID   1651
#define HIDP  1664      // 13*128, zero-padded
#define BATCH 4096
#define BK    64
#define KT_TOTAL 129    // FEAT / BK (full K, no split: relu needs full sum)
#define W1SCALE 8192.0f
#define W1INV   (1.0f / 8192.0f)
#define DEPTH 3         // LDS ring buffers (2-iteration prefetch lead)

using f32x4  = __attribute__((ext_vector_type(4))) float;
using f32x16 = __attribute__((ext_vector_type(16))) float;
using i32x4  = __attribute__((ext_vector_type(4))) int;
using i32x8  = __attribute__((ext_vector_type(8))) int;
typedef long long i64;

__device__ __forceinline__ void gload_lds16(const void* g, void* l) {
    __builtin_amdgcn_global_load_lds(
        (const __attribute__((address_space(1))) void*)g,
        (__attribute__((address_space(3))) void*)l,
        16, 0, 0);
}

__device__ __forceinline__ int row_off(int i) { return (i * (257 - i)) >> 1; }

// pack 8 floats -> 8 fp8 e4m3 bytes (two ints)
__device__ __forceinline__ void pack8_fp8(const float* f, int* o) {
    int lo = __builtin_amdgcn_cvt_pk_fp8_f32(f[0], f[1], 0, false);
    lo     = __builtin_amdgcn_cvt_pk_fp8_f32(f[2], f[3], lo, true);
    int hi = __builtin_amdgcn_cvt_pk_fp8_f32(f[4], f[5], 0, false);
    hi     = __builtin_amdgcn_cvt_pk_fp8_f32(f[6], f[7], hi, true);
    o[0] = lo; o[1] = hi;
}

// ---------------------------------------------------------------------------
// Kernel 1 (fused prep): blocks [0, BATCH) gather triu(sim) -> X fp8;
// blocks [BATCH, BATCH+5*HIDP) convert W1*8192 -> fp8 [HIDP, FEAT] (rows >=
// HID zeroed); final block zeroes out_pre[4096] for the GEMM's atomics.
// ---------------------------------------------------------------------------
__global__ void __launch_bounds__(256)
prep_kernel(const float* __restrict__ sim, const float* __restrict__ W1,
            char* __restrict__ X, char* __restrict__ W1p,
            float* __restrict__ out_pre) {
    const int t = threadIdx.x;
    if (blockIdx.x < BATCH) {
        const int b = blockIdx.x;
        const float* srow = sim + ((i64)b << 14);
        char* dst = X + (i64)b * FEAT;
#pragma unroll
        for (int it = 0; it < 5; ++it) {
            const int w = it * 256 + t;
            if (w < FEAT / 8) {
                const int f0 = w * 8;
                int i = (int)((257.0f - sqrtf(66049.0f - 8.0f * (float)f0)) * 0.5f);
                i = i < 0 ? 0 : (i > 127 ? 127 : i);
                while (i < 127 && row_off(i + 1) <= f0) ++i;
                while (i > 0 && row_off(i) > f0) --i;
                int j = i + (f0 - row_off(i));
                float v[8];
#pragma unroll
                for (int e = 0; e < 8; ++e) {
                    if (j > 127) { ++i; j = i; }
                    v[e] = srow[i * MDIM + j];
                    ++j;
                }
                int o[2];
                pack8_fp8(v, o);
                *(int2*)(dst + f0) = make_int2(o[0], o[1]);
            }
        }
    } else if (blockIdx.x < BATCH + 5 * HIDP) {
        const int c  = blockIdx.x - BATCH;   // 0 .. 5*HIDP-1
        const int wb = c % 5;
        const int n  = c / 5;
        const int w  = wb * 256 + t;
        if (w >= FEAT / 8) return;
        const int f0 = w * 8;
        int o[2];
        if (n < HID) {
            const float* src = W1 + (i64)n * FEAT + f0;
            const f32x4 a = *(const f32x4*)src;
            const f32x4 d = *(const f32x4*)(src + 4);
            float v[8];
#pragma unroll
            for (int e = 0; e < 4; ++e) {
                v[e]     = a[e] * W1SCALE;
                v[e + 4] = d[e] * W1SCALE;
            }
            pack8_fp8(v, o);
        } else {
            o[0] = 0; o[1] = 0;
        }
        *(int2*)(W1p + (i64)n * FEAT + f0) = make_int2(o[0], o[1]);
    } else {
        // zero out_pre (4096 floats = 1024 f32x4; 4 per thread)
        const f32x4 zz = {0.f, 0.f, 0.f, 0.f};
        f32x4* p = (f32x4*)out_pre + t * 4;
        p[0] = zz; p[1] = zz; p[2] = zz; p[3] = zz;
    }
}

// ---------------------------------------------------------------------------
// Kernel 2: full-K MX-scaled fp8 GEMM, 128x128 tile, BK=64, FUSED epilogue.
// Ring pipeline (DEPTH=3) + raw s_barrier + counted vmcnt (verified r2).
// After the K-loop each wave applies relu(acc*W1INV + b1)*W2 in-register,
// half-wave shfl_xor-reduces its 64 columns, and atomicAdds one fp32 partial
// per output row -> out_pre[4096]. Kills the 27 MB Cz write + 27 MB re-read
// + 64 scalar bf16 stores/lane of the old epilogue path.
//
// LDS layout (HW-verified r1/r2): phys(row,chunk)=chunk*2048+row*16; staging
// realizes it via per-lane global source chunk choice; fragment reads are
// conflict-free ds_read_b128 pairs.
// ---------------------------------------------------------------------------
__global__ void __launch_bounds__(256, 3)
gemm_fused_kernel(const char* __restrict__ X,
                  const char* __restrict__ W1p,
                  const float* __restrict__ b1,
                  const float* __restrict__ W2,
                  float* __restrict__ out_pre) {
    __shared__ __align__(16) char lds_a[DEPTH * 8192];   // 24 KB
    __shared__ __align__(16) char lds_b[DEPTH * 8192];   // 24 KB

    const int t    = threadIdx.x;
    const int w    = t >> 6;
    const int l    = t & 63;
    const int bm   = blockIdx.x;
    const int bn   = blockIdx.y;
    const int wm   = w >> 1;          // wave row (0..1) -> 64 output rows
    const int wn   = w & 1;           // wave col (0..1) -> 64 output cols
    const int lm   = l & 31;
    const int c0   = (l >> 5) << 1;   // chunk base for this lane's K-half

    f32x16 acc[2][2];
#pragma unroll
    for (int r = 0; r < 16; ++r) {
        acc[0][0][r] = 0.f; acc[0][1][r] = 0.f;
        acc[1][0][r] = 0.f; acc[1][1][r] = 0.f;
    }

    const int nkt = KT_TOTAL;

    // staging roles: thread t covers row (w&1)*64+l, chunks {(w>>1), (w>>1)+2}
    const int stR = ((w & 1) << 6) + l;
    const char* gA0 = X + (i64)(bm * 128 + stR) * FEAT + (w >> 1) * 16;
    const char* gB0 = W1p + (i64)(bn * 128 + stR) * FEAT + (w >> 1) * 16;
    char* lA = lds_a + w * 1024;      // wave-uniform LDS dest base
    char* lB = lds_b + w * 1024;

    // 4 vmcnt events (global_load_lds) per STAGE per thread
#define STAGE(buf, kidx) do {                                      \
        const char* _ga = gA0 + (i64)(kidx) * BK;                  \
        const char* _gb = gB0 + (i64)(kidx) * BK;                  \
        char* _la = lA + (buf) * 8192;                             \
        char* _lb = lB + (buf) * 8192;                             \
        gload_lds16(_ga,      _la);                                \
        gload_lds16(_ga + 32, _la + 4096);                         \
        gload_lds16(_gb,      _lb);                                \
        gload_lds16(_gb + 32, _lb + 4096);                         \
    } while (0)

    STAGE(0, 0);
    STAGE(1, 1);
    STAGE(2, 2);

    int cur = 0;
    for (int kt = 0; kt < nkt; ++kt) {
        // ready-wait for buf[cur]: drain my oldest stage, keep the rest flying
        if (kt + 3 <= nkt)      asm volatile("s_waitcnt vmcnt(8)" ::: "memory");
        else if (kt + 2 == nkt) asm volatile("s_waitcnt vmcnt(4)" ::: "memory");
        else                    asm volatile("s_waitcnt vmcnt(0)" ::: "memory");
        __builtin_amdgcn_s_barrier();          // all waves' quarters landed
        __builtin_amdgcn_sched_barrier(0);

        const char* pa = lds_a + cur * 8192 + c0 * 2048 + (wm * 64 + lm) * 16;
        const char* pb = lds_b + cur * 8192 + c0 * 2048 + (wn * 64 + lm) * 16;
        i32x8 A0, A1, B0, B1;
        *((i32x4*)&A0)     = *(const i32x4*)(pa);
        *((i32x4*)&A0 + 1) = *(const i32x4*)(pa + 2048);
        *((i32x4*)&A1)     = *(const i32x4*)(pa + 512);
        *((i32x4*)&A1 + 1) = *(const i32x4*)(pa + 512 + 2048);
        *((i32x4*)&B0)     = *(const i32x4*)(pb);
        *((i32x4*)&B0 + 1) = *(const i32x4*)(pb + 2048);
        *((i32x4*)&B1)     = *(const i32x4*)(pb + 512);
        *((i32x4*)&B1 + 1) = *(const i32x4*)(pb + 512 + 2048);

        __builtin_amdgcn_s_setprio(1);
        // fmt 0 = OCP fp8 e4m3; unit scales (0x7F = 2^0) in every byte
        acc[0][0] = __builtin_amdgcn_mfma_scale_f32_32x32x64_f8f6f4(
            A0, B0, acc[0][0], 0, 0, 0, 0x7F7F7F7F, 0, 0x7F7F7F7F);
        acc[0][1] = __builtin_amdgcn_mfma_scale_f32_32x32x64_f8f6f4(
            A0, B1, acc[0][1], 0, 0, 0, 0x7F7F7F7F, 0, 0x7F7F7F7F);
        acc[1][0] = __builtin_amdgcn_mfma_scale_f32_32x32x64_f8f6f4(
            A1, B0, acc[1][0], 0, 0, 0, 0x7F7F7F7F, 0, 0x7F7F7F7F);
        acc[1][1] = __builtin_amdgcn_mfma_scale_f32_32x32x64_f8f6f4(
            A1, B1, acc[1][1], 0, 0, 0, 0x7F7F7F7F, 0, 0x7F7F7F7F);
        __builtin_amdgcn_s_setprio(0);

        // my ds_reads retired before anyone overwrites buf[cur]
        asm volatile("s_waitcnt lgkmcnt(0)" ::: "memory");
        __builtin_amdgcn_sched_barrier(0);
        __builtin_amdgcn_s_barrier();          // all waves done reading cur
        __builtin_amdgcn_sched_barrier(0);

        if (kt + 3 < nkt) STAGE(cur, kt + 3);  // refill oldest slot
        cur = (cur == DEPTH - 1) ? 0 : cur + 1;
    }
#undef STAGE

    // ---- fused epilogue ----
    // C/D mapping: col = lane&31, row = (reg&3) + 8*(reg>>2) + 4*(lane>>5).
    // Each lane owns cols {colbase, colbase+32}; rows iterate over (rb,reg).
    const int colbase = bn * 128 + wn * 64 + lm;
    float b1v[2], w2v[2];
#pragma unroll
    for (int cb = 0; cb < 2; ++cb) {
        const int col = colbase + cb * 32;
        const bool ok = col < HID;          // padded cols contribute 0
        b1v[cb] = ok ? b1[col] : 0.f;
        w2v[cb] = ok ? W2[col] : 0.f;
    }
    const int rbase = bm * 128 + wm * 64 + ((l >> 5) << 2);
#pragma unroll
    for (int rb = 0; rb < 2; ++rb)
#pragma unroll
        for (int reg = 0; reg < 16; ++reg) {
            float v = 0.f;
#pragma unroll
            for (int cb = 0; cb < 2; ++cb) {
                const float pre = acc[rb][cb][reg] * W1INV + b1v[cb];
                v += fmaxf(pre, 0.f) * w2v[cb];
            }
            // reduce over this half-wave's 32 columns (masks stay in-half)
            v += __shfl_xor(v, 1);
            v += __shfl_xor(v, 2);
            v += __shfl_xor(v, 4);
            v += __shfl_xor(v, 8);
            v += __shfl_xor(v, 16);
            if (lm == 0) {
                const int row = rbase + rb * 32 + (reg & 3) + ((reg >> 2) << 3);
                atomicAdd(out_pre + row, v);
            }
        }
}

// ---------------------------------------------------------------------------
// Kernel 3: out[b] = sigmoid(out_pre[b] + b2)
// ---------------------------------------------------------------------------
__global__ void __launch_bounds__(256)
sigmoid_kernel(const float* __restrict__ pre,
               const float* __restrict__ b2,
               float* __restrict__ out) {
    const int i = blockIdx.x * 256 + threadIdx.x;
    out[i] = 1.0f / (1.0f + expf(-(pre[i] + b2[0])));
}

extern "C" void kernel_launch(void* const* d_in, const int* in_sizes, int n_in,
                              void* d_out, int out_size, void* d_ws, size_t ws_size,
                              hipStream_t stream) {
    const float* sim = (const float*)d_in[0];
    const float* W1  = (const float*)d_in[1];
    const float* b1  = (const float*)d_in[2];
    const float* W2  = (const float*)d_in[3];
    const float* b2  = (const float*)d_in[4];
    float* out = (float*)d_out;

    char* ws = (char*)d_ws;
    const i64 X_OFF   = 0;                           // 33,816,576 B
    const i64 W1P_OFF = (i64)BATCH * FEAT;           // fp8: elems == bytes
    const i64 PRE_OFF = W1P_OFF + (i64)HIDP * FEAT;  // +13,737,984
    // total: 47,554,560 + 16,384 B << ws bound
    char*  Xf8  = ws + X_OFF;
    char*  W1f8 = ws + W1P_OFF;
    float* pre  = (float*)(ws + PRE_OFF);

    prep_kernel<<<BATCH + 5 * HIDP + 1, 256, 0, stream>>>(sim, W1, Xf8, W1f8, pre);
    {
        dim3 grid(BATCH / 128, HIDP / 128);          // (32, 13)
        gemm_fused_kernel<<<grid, 256, 0, stream>>>(Xf8, W1f8, b1, W2, pre);
    }
    sigmoid_kernel<<<BATCH / 256, 256, 0, stream>>>(pre, b2, out);
}